// Round 11
// baseline (393.381 us; speedup 1.0000x reference)
//
#include <hip/hip_runtime.h>

// GraphPooling: B=8, N=3072, D=1024, POOL=3, steps=1024
//  out[b, 2k,   d] = (sum x[b, s..e, d]) / (e-s+1) + 0.006
//  out[b, 2k+1, d] = mean(x[b, 3k:3k+3, d])
//
// Round-15 (2nd resubmit; R9+R10 benches were GPU-acquisition timeouts):
// 2 real kernels (K2 folded into K1 via last-block-per-batch).
//  R14 (-11 us) calibrated small-kernel+gap cost at ~10 us. K2 is the last
//  such kernel. Eliminate it WITHOUT spinning (R7 lesson: spin-wait
//  acquire loads = invalidate storm): each K1 block does ONE acq_rel
//  atomicAdd on a per-batch counter after threadfence; the block that sees
//  count==127 (all P rows published) serially scans P -> O (128 L2-hot
//  rows, ~3 us, 8 such blocks in parallel, one per batch). Counter
//  zero-init via 32-byte hipMemsetAsync (ws is poisoned each iter).
//  K1/K4 bodies identical to R14. O now summed serially (reference-like
//  order) -> absmax may shift, expected <= 0.0039.

constexpr int Bdim  = 8;
constexpr int Nn    = 3072;
constexpr int Dd    = 1024;
constexpr int STEPS = 1024;   // windows
constexpr int CHW   = 8;      // windows per chunk
constexpr int CHR   = 24;     // rows per chunk
constexpr int NCH   = 128;    // STEPS / CHW
constexpr int KT    = 4;      // steps per K4 block
constexpr int NKT   = 256;    // STEPS / KT
constexpr int D4    = Dd / 4; // 256 float4 per row
constexpr int RCAP  = 16;     // max events per row
constexpr float EPS = 0.006f;

constexpr size_t T_E = (size_t)Bdim * 2 * STEPS * Dd;     // 64 MB (floats)
constexpr size_t P_E = (size_t)Bdim * NCH * Dd;           //  4 MB
constexpr size_t O_E = (size_t)Bdim * (NCH + 1) * Dd;     //  4.2 MB

typedef float nat_f4 __attribute__((ext_vector_type(4)));

__device__ __forceinline__ float4 f4add(float4 a, float4 b) {
    return make_float4(a.x + b.x, a.y + b.y, a.z + b.z, a.w + b.w);
}

__device__ __forceinline__ float4 f4sel(bool c, float4 a, float4 b) {
    return make_float4(c ? a.x : b.x, c ? a.y : b.y,
                       c ? a.z : b.z, c ? a.w : b.w);
}

__device__ __forceinline__ void nt_store(float4 v, float4* p) {
    nat_f4 nv = {v.x, v.y, v.z, v.w};
    __builtin_nontemporal_store(nv, reinterpret_cast<nat_f4*>(p));
}

__device__ __forceinline__ float4 nt_load(const float4* p) {
    nat_f4 nv = __builtin_nontemporal_load(reinterpret_cast<const nat_f4*>(p));
    return make_float4(nv.x, nv.y, nv.z, nv.w);
}

// ---------------- K1: self-bucket + scan + push + last-block O-scan ------
__global__ __launch_bounds__(256)
void k1_scan(const float4* __restrict__ x4, const int* __restrict__ graph,
             float4* __restrict__ out4, float4* __restrict__ T4,
             float4* __restrict__ P4, float4* __restrict__ O4,
             int* __restrict__ cnt) {
    const int t  = threadIdx.x;          // float4 column 0..255
    const int ch = blockIdx.x;           // 0..127
    const int b  = blockIdx.y;           // 0..7
    const int k0 = ch * CHW;
    const int r0 = ch * CHR;
    const float4 z4 = make_float4(0.f, 0.f, 0.f, 0.f);

    // ---- issue the 24 x row loads first (latency overlaps bucketing) ----
    const float4* xp = x4 + ((size_t)(b * Nn + r0)) * D4 + t;
    float4 v[CHR];
#pragma unroll
    for (int i = 0; i < CHR; ++i)
        v[i] = nt_load(&xp[(size_t)i * D4]);

    // ---- self-bucket: events (query rows) landing in [r0, r0+CHR) ----
    __shared__ int scnt[CHR];
    __shared__ int lst[CHR][RCAP];
    if (t < CHR) scnt[t] = 0;
    __syncthreads();
    for (int k = t; k < STEPS; k += 256) {
        const int2 se = *reinterpret_cast<const int2*>(
            graph + ((size_t)(b * STEPS + k)) * 2);
        const int js = se.x - r0;                // start snapshot row
        if (js >= 0 && js < CHR) {
            int p = atomicAdd(&scnt[js], 1);
            if (p < RCAP) lst[js][p] = 2 * k;
        }
        const int je = se.y + 1 - r0;            // end snapshot row
        if (je >= 0 && je < CHR) {
            int p = atomicAdd(&scnt[je], 1);
            if (p < RCAP) lst[je][p] = 2 * k + 1;
        }
    }
    __syncthreads();

    // ---- window means -> odd output rows ----
    float4* op = out4 + ((size_t)b * 2 * STEPS) * D4 + t;
#pragma unroll
    for (int wi = 0; wi < CHW; ++wi) {
        float4 w = f4add(f4add(v[3 * wi], v[3 * wi + 1]), v[3 * wi + 2]);
        float4 wm = make_float4(w.x * (1.f / 3.f), w.y * (1.f / 3.f),
                                w.z * (1.f / 3.f), w.w * (1.f / 3.f));
        nt_store(wm, &op[(size_t)(2 * (k0 + wi) + 1) * D4]);
    }

    // ---- within-chunk exclusive prefix; push snapshots at event rows ----
    float4* Tb = T4 + ((size_t)b * 2 * STEPS) * D4 + t;
    float4 run = z4;
#pragma unroll
    for (int j = 0; j < CHR; ++j) {
        const int nj = min(scnt[j], RCAP);       // uniform (LDS broadcast)
        for (int q = 0; q < nj; ++q)             // usually 0 or 1
            Tb[(size_t)lst[j][q] * D4] = run;    // coalesced 4 KB row
        run = f4add(run, v[j]);
    }
    P4[((size_t)b * NCH + ch) * D4 + t] = run;   // chunk total

    // ---- tail: last-arriving block of batch b scans P -> O ----
    //  ONE atomic per block (no spin). threadfence + acq_rel atomic makes
    //  all 128 blocks' P rows visible to the single reader block.
    __threadfence();
    __syncthreads();
    __shared__ int s_last;
    if (t == 0) {
        int old = __hip_atomic_fetch_add(&cnt[b], 1, __ATOMIC_ACQ_REL,
                                         __HIP_MEMORY_SCOPE_AGENT);
        s_last = (old == NCH - 1);
    }
    __syncthreads();
    if (s_last) {
        const float4* pb = P4 + (size_t)b * NCH * D4 + t;
        float4*       o  = O4 + (size_t)b * (NCH + 1) * D4 + t;
        float4 run2 = z4;
        for (int c = 0; c < NCH; c += 4) {       // prefetch 4 rows ahead
            float4 p0 = pb[(size_t)(c + 0) * D4];
            float4 p1 = pb[(size_t)(c + 1) * D4];
            float4 p2 = pb[(size_t)(c + 2) * D4];
            float4 p3 = pb[(size_t)(c + 3) * D4];
            o[(size_t)(c + 0) * D4] = run2;  run2 = f4add(run2, p0);
            o[(size_t)(c + 1) * D4] = run2;  run2 = f4add(run2, p1);
            o[(size_t)(c + 2) * D4] = run2;  run2 = f4add(run2, p2);
            o[(size_t)(c + 3) * D4] = run2;  run2 = f4add(run2, p3);
        }
        o[(size_t)NCH * D4] = run2;              // grand total = c[N]
    }
}

// ---------------- K4: streaming combine ----------------
//  out[2k] = (O[ch(e+1)] + T[2k+1] - O[ch(s)] - T[2k]) * inv + EPS
__global__ __launch_bounds__(256)
void k4_combine(const float4* __restrict__ T4, const float4* __restrict__ O4,
                const int* __restrict__ graph, float4* __restrict__ out4) {
    const int t  = threadIdx.x;
    const int kt = blockIdx.x;                 // 0..255
    const int b  = blockIdx.y;

    const int* gp = graph + ((size_t)(b * STEPS + kt * KT)) * 2;
    const int4 ga = *reinterpret_cast<const int4*>(gp);
    const int4 gb = *reinterpret_cast<const int4*>(gp + 4);
    const int sA[KT] = {ga.x, ga.z, gb.x, gb.z};
    const int eA[KT] = {ga.y, ga.w, gb.y, gb.w};

    const float4* Tb = T4 + (size_t)b * 2 * STEPS * D4 + t;
    const float4* oc = O4 + (size_t)b * (NCH + 1) * D4 + t;
    float4*       ob = out4 + (size_t)b * 2 * STEPS * D4 + t;

    // ---- issue ALL loads before any combine ----
    float4 ts[KT], te[KT], o1[KT], o2[KT];
    int ieA[KT];
    const float4 tot = oc[(size_t)NCH * D4];   // grand total row (hot)
#pragma unroll
    for (int u = 0; u < KT; ++u) {
        const int k = kt * KT + u;
        ts[u] = Tb[(size_t)(2 * k) * D4];      // sequential streaming rows
        te[u] = Tb[(size_t)(2 * k + 1) * D4];
        const int s = sA[u];
        const int ie = eA[u] + 1;  ieA[u] = ie;            // 1..3072
        o1[u] = oc[(size_t)(s / CHR) * D4];                // hot 4.2 MB table
        const int c2 = ie < Nn ? ie / CHR : 0;             // clamp (sel'd away)
        o2[u] = oc[(size_t)c2 * D4];
    }

    // ---- combine + store ----
#pragma unroll
    for (int u = 0; u < KT; ++u) {
        float4 cs = f4add(o1[u], ts[u]);
        float4 ce = f4sel(ieA[u] < Nn, f4add(o2[u], te[u]), tot);

        float inv = 1.f / (float)(eA[u] - sA[u] + 1);
        float4 res = make_float4((ce.x - cs.x) * inv + EPS,
                                 (ce.y - cs.y) * inv + EPS,
                                 (ce.z - cs.z) * inv + EPS,
                                 (ce.w - cs.w) * inv + EPS);
        const int k = kt * KT + u;
        nt_store(res, &ob[(size_t)(2 * k) * D4]);   // even output row
    }
}

extern "C" void kernel_launch(void* const* d_in, const int* in_sizes, int n_in,
                              void* d_out, int out_size, void* d_ws, size_t ws_size,
                              hipStream_t stream) {
    const float* x     = (const float*)d_in[0];
    const int*   graph = (const int*)d_in[1];
    float*       out   = (float*)d_out;

    float* T = (float*)d_ws;
    float* P = T + T_E;
    float* O = P + P_E;
    int*   cnt = (int*)(O + O_E);

    // zero the 8 per-batch completion counters (ws is poisoned each iter)
    hipMemsetAsync(cnt, 0, Bdim * sizeof(int), stream);

    dim3 g1(NCH, Bdim);          // (128, 8) = 1024 blocks
    k1_scan<<<g1, 256, 0, stream>>>((const float4*)x, graph, (float4*)out,
                                    (float4*)T, (float4*)P, (float4*)O, cnt);
    dim3 g4(NKT, Bdim);          // (256, 8) = 2048 blocks
    k4_combine<<<g4, 256, 0, stream>>>((const float4*)T, (const float4*)O,
                                       graph, (float4*)out);
}

// Round 17
// 187.208 us; speedup vs baseline: 2.1013x; 2.1013x over previous
//
#include <hip/hip_runtime.h>

// GraphPooling: B=8, N=3072, D=1024, POOL=3, steps=1024
//  out[b, 2k,   d] = (sum x[b, s..e, d]) / (e-s+1) + 0.006
//  out[b, 2k+1, d] = mean(x[b, 3k:3k+3, d])
//
// Round-16 (6th resubmit; R12-R16 benches were GPU-acquisition timeouts):
// R14 structure (3 kernels, best measured 182.3 us) with K1
//  rewritten as a streaming 1-window software pipeline.
//  - R11/R7 verdict: ANY device-side cross-block sync (spin OR single
//    acq_rel atomic + last-block) costs 100+ us on gfx950. Launch
//    boundaries are ~10 us. K2 stays a separate kernel. Forever.
//  - R11 clue: old K1 held v[24] float4 (96 regs) in a 64-VGPR budget ->
//    spill/reload strangled the load pipeline (R4 fused phase showed 17%
//    HBM). New K1 streams: 3 current + 3 prefetched rows + run = ~8
//    float4 live, named ping-pong regs (static indexing), next-window
//    loads issued BEFORE current window's LDS-dependent snapshot work.
//  - K2/K4 byte-identical to R14. Same row-add order -> absmax 0.00195.

constexpr int Bdim  = 8;
constexpr int Nn    = 3072;
constexpr int Dd    = 1024;
constexpr int STEPS = 1024;   // windows
constexpr int CHW   = 8;      // windows per chunk
constexpr int CHR   = 24;     // rows per chunk
constexpr int NCH   = 128;    // STEPS / CHW
constexpr int KT    = 4;      // steps per K4 block
constexpr int NKT   = 256;    // STEPS / KT
constexpr int D4    = Dd / 4; // 256 float4 per row
constexpr int RCAP  = 16;     // max events per row
constexpr float EPS = 0.006f;

constexpr size_t T_E = (size_t)Bdim * 2 * STEPS * Dd;     // 64 MB (floats)
constexpr size_t P_E = (size_t)Bdim * NCH * Dd;           //  4 MB

typedef float nat_f4 __attribute__((ext_vector_type(4)));

__device__ __forceinline__ float4 f4add(float4 a, float4 b) {
    return make_float4(a.x + b.x, a.y + b.y, a.z + b.z, a.w + b.w);
}

__device__ __forceinline__ float4 f4sel(bool c, float4 a, float4 b) {
    return make_float4(c ? a.x : b.x, c ? a.y : b.y,
                       c ? a.z : b.z, c ? a.w : b.w);
}

__device__ __forceinline__ void nt_store(float4 v, float4* p) {
    nat_f4 nv = {v.x, v.y, v.z, v.w};
    __builtin_nontemporal_store(nv, reinterpret_cast<nat_f4*>(p));
}

__device__ __forceinline__ float4 nt_load(const float4* p) {
    nat_f4 nv = __builtin_nontemporal_load(reinterpret_cast<const nat_f4*>(p));
    return make_float4(nv.x, nv.y, nv.z, nv.w);
}

// ---------------- K1: self-bucket + STREAMING scan + snapshot push -------
__global__ __launch_bounds__(256)
void k1_scan(const float4* __restrict__ x4, const int* __restrict__ graph,
             float4* __restrict__ out4, float4* __restrict__ T4,
             float4* __restrict__ P4) {
    const int t  = threadIdx.x;          // float4 column 0..255
    const int ch = blockIdx.x;           // 0..127
    const int b  = blockIdx.y;           // 0..7
    const int k0 = ch * CHW;
    const int r0 = ch * CHR;
    const float4 z4 = make_float4(0.f, 0.f, 0.f, 0.f);

    const float4* xp = x4 + ((size_t)(b * Nn + r0)) * D4 + t;

    // ---- prologue: window-0 loads in flight during bucketing ----
    float4 a = nt_load(&xp[0 * D4]);
    float4 bb = nt_load(&xp[1 * D4]);
    float4 c = nt_load(&xp[2 * D4]);

    // ---- self-bucket: events (query rows) landing in [r0, r0+CHR) ----
    __shared__ int scnt[CHR];
    __shared__ int lst[CHR][RCAP];
    if (t < CHR) scnt[t] = 0;
    __syncthreads();
    for (int k = t; k < STEPS; k += 256) {
        const int2 se = *reinterpret_cast<const int2*>(
            graph + ((size_t)(b * STEPS + k)) * 2);
        const int js = se.x - r0;                // start snapshot row
        if (js >= 0 && js < CHR) {
            int p = atomicAdd(&scnt[js], 1);
            if (p < RCAP) lst[js][p] = 2 * k;
        }
        const int je = se.y + 1 - r0;            // end snapshot row
        if (je >= 0 && je < CHR) {
            int p = atomicAdd(&scnt[je], 1);
            if (p < RCAP) lst[je][p] = 2 * k + 1;
        }
    }
    __syncthreads();

    // ---- streaming scan: 1-window lookahead, named ping-pong regs ----
    float4* op = out4 + ((size_t)b * 2 * STEPS) * D4 + t;
    float4* Tb = T4 + ((size_t)b * 2 * STEPS) * D4 + t;
    float4 run = z4;
#pragma unroll
    for (int w = 0; w < CHW; ++w) {
        // issue next window's 3 loads first (in flight during LDS work)
        float4 na, nb, nc;
        if (w < CHW - 1) {
            na = nt_load(&xp[(size_t)(3 * w + 3) * D4]);
            nb = nt_load(&xp[(size_t)(3 * w + 4) * D4]);
            nc = nt_load(&xp[(size_t)(3 * w + 5) * D4]);
        }
        // window mean -> odd output row
        float4 s3 = f4add(f4add(a, bb), c);
        float4 wm = make_float4(s3.x * (1.f / 3.f), s3.y * (1.f / 3.f),
                                s3.z * (1.f / 3.f), s3.w * (1.f / 3.f));
        nt_store(wm, &op[(size_t)(2 * (k0 + w) + 1) * D4]);
        // snapshots (exclusive prefix) + sequential adds, rows 3w..3w+2
        {
            const int j = 3 * w;
            const int nj = min(scnt[j], RCAP);
            for (int q = 0; q < nj; ++q)
                Tb[(size_t)lst[j][q] * D4] = run;
            run = f4add(run, a);
        }
        {
            const int j = 3 * w + 1;
            const int nj = min(scnt[j], RCAP);
            for (int q = 0; q < nj; ++q)
                Tb[(size_t)lst[j][q] * D4] = run;
            run = f4add(run, bb);
        }
        {
            const int j = 3 * w + 2;
            const int nj = min(scnt[j], RCAP);
            for (int q = 0; q < nj; ++q)
                Tb[(size_t)lst[j][q] * D4] = run;
            run = f4add(run, c);
        }
        a = na; bb = nb; c = nc;
    }
    P4[((size_t)b * NCH + ch) * D4 + t] = run;   // chunk total
}

// ---------------- K2: 2-level scan of chunk totals -> exclusive prefix O ----
__global__ __launch_bounds__(256)
void k2_chscan(const float4* __restrict__ P4, float4* __restrict__ O4) {
    __shared__ float4 part[8][33];
    const int cw  = threadIdx.x & 31;          // f4-col within tile
    const int seg = threadIdx.x >> 5;          // 0..7 -> 16 chunks each
    const int col = blockIdx.x * 32 + cw;
    const int b   = blockIdx.y;

    const float4* p = P4 + (size_t)b * NCH * D4 + col;
    float4 v[16];
    float4 sum = make_float4(0.f, 0.f, 0.f, 0.f);
#pragma unroll
    for (int i = 0; i < 16; ++i) {
        v[i] = p[(size_t)(seg * 16 + i) * D4];
        sum = f4add(sum, v[i]);
    }
    part[seg][cw] = sum;
    __syncthreads();
    if (threadIdx.x < 32) {
        float4 run = make_float4(0.f, 0.f, 0.f, 0.f);
#pragma unroll
        for (int s = 0; s < 8; ++s) {
            float4 t2 = part[s][threadIdx.x];
            part[s][threadIdx.x] = run;
            run = f4add(run, t2);
        }
    }
    __syncthreads();
    float4 run = part[seg][cw];
    float4* o = O4 + (size_t)b * (NCH + 1) * D4 + col;
#pragma unroll
    for (int i = 0; i < 16; ++i) {
        o[(size_t)(seg * 16 + i) * D4] = run;
        run = f4add(run, v[i]);
    }
    if (seg == 7) o[(size_t)NCH * D4] = run;   // grand total = c[N]
}

// ---------------- K4: streaming combine ----------------
//  out[2k] = (O[ch(e+1)] + T[2k+1] - O[ch(s)] - T[2k]) * inv + EPS
__global__ __launch_bounds__(256)
void k4_combine(const float4* __restrict__ T4, const float4* __restrict__ O4,
                const int* __restrict__ graph, float4* __restrict__ out4) {
    const int t  = threadIdx.x;
    const int kt = blockIdx.x;                 // 0..255
    const int b  = blockIdx.y;

    const int* gp = graph + ((size_t)(b * STEPS + kt * KT)) * 2;
    const int4 ga = *reinterpret_cast<const int4*>(gp);
    const int4 gb = *reinterpret_cast<const int4*>(gp + 4);
    const int sA[KT] = {ga.x, ga.z, gb.x, gb.z};
    const int eA[KT] = {ga.y, ga.w, gb.y, gb.w};

    const float4* Tb = T4 + (size_t)b * 2 * STEPS * D4 + t;
    const float4* oc = O4 + (size_t)b * (NCH + 1) * D4 + t;
    float4*       ob = out4 + (size_t)b * 2 * STEPS * D4 + t;

    // ---- issue ALL loads before any combine ----
    float4 ts[KT], te[KT], o1[KT], o2[KT];
    int ieA[KT];
    const float4 tot = oc[(size_t)NCH * D4];   // grand total row (hot)
#pragma unroll
    for (int u = 0; u < KT; ++u) {
        const int k = kt * KT + u;
        ts[u] = Tb[(size_t)(2 * k) * D4];      // sequential streaming rows
        te[u] = Tb[(size_t)(2 * k + 1) * D4];
        const int s = sA[u];
        const int ie = eA[u] + 1;  ieA[u] = ie;            // 1..3072
        o1[u] = oc[(size_t)(s / CHR) * D4];                // hot 4.2 MB table
        const int c2 = ie < Nn ? ie / CHR : 0;             // clamp (sel'd away)
        o2[u] = oc[(size_t)c2 * D4];
    }

    // ---- combine + store ----
#pragma unroll
    for (int u = 0; u < KT; ++u) {
        float4 cs = f4add(o1[u], ts[u]);
        float4 ce = f4sel(ieA[u] < Nn, f4add(o2[u], te[u]), tot);

        float inv = 1.f / (float)(eA[u] - sA[u] + 1);
        float4 res = make_float4((ce.x - cs.x) * inv + EPS,
                                 (ce.y - cs.y) * inv + EPS,
                                 (ce.z - cs.z) * inv + EPS,
                                 (ce.w - cs.w) * inv + EPS);
        const int k = kt * KT + u;
        nt_store(res, &ob[(size_t)(2 * k) * D4]);   // even output row
    }
}

extern "C" void kernel_launch(void* const* d_in, const int* in_sizes, int n_in,
                              void* d_out, int out_size, void* d_ws, size_t ws_size,
                              hipStream_t stream) {
    const float* x     = (const float*)d_in[0];
    const int*   graph = (const int*)d_in[1];
    float*       out   = (float*)d_out;

    float* T = (float*)d_ws;
    float* P = T + T_E;
    float* O = P + P_E;

    dim3 g1(NCH, Bdim);          // (128, 8) = 1024 blocks
    k1_scan<<<g1, 256, 0, stream>>>((const float4*)x, graph, (float4*)out,
                                    (float4*)T, (float4*)P);
    dim3 g2(D4 / 32, Bdim);      // (8, 8) = 64 blocks
    k2_chscan<<<g2, 256, 0, stream>>>((const float4*)P, (float4*)O);
    dim3 g4(NKT, Bdim);          // (256, 8) = 2048 blocks
    k4_combine<<<g4, 256, 0, stream>>>((const float4*)T, (const float4*)O,
                                       graph, (float4*)out);
}